// Round 1
// baseline (221.848 us; speedup 1.0000x reference)
//
#include <hip/hip_runtime.h>
#include <hip/hip_bf16.h>

// MHA: B=2, S=2048, D=1024, H=16, dk=64.  M = B*S = 4096.
// ws layout (bytes):
//   0: Wt_q (2MB) | 2MB: Wt_k | 4MB: Wt_v | 6MB: Wt_o      bf16 [out][in]
//   8MB: Qh  [B,H,S,64] bf16 (pre-scaled by 0.125)
//  16MB: Kh  [B,H,S,64] bf16
//  24MB: Vt  [B,H,64,S] bf16 (V transposed per head)
//  32MB: ctx [B,S,D]    bf16
// total 40MB of d_ws.

typedef __bf16 bf16x8 __attribute__((ext_vector_type(8)));
typedef float  f32x4  __attribute__((ext_vector_type(4)));

#define DEVI __device__ __forceinline__
// XOR swizzle: 16B-chunk index of a 128B row XORed with (row&7) -> conflict-free
// ds_read_b128 column access (guide §6 G4).
#define SWZ(row, cb) ((cb) ^ (((row) & 7) << 4))

static DEVI unsigned short f2bf(float f) {
    __hip_bfloat16 h = __float2bfloat16(f);
    return __builtin_bit_cast(unsigned short, h);
}
static DEVI unsigned int pack2(float a, float b) {
    return (unsigned int)f2bf(a) | ((unsigned int)f2bf(b) << 16);
}
static DEVI bf16x8 ldsRead(const char* p) {
    return __builtin_bit_cast(bf16x8, *(const uint4*)p);
}

// ---------------------------------------------------------------------------
// Kernel 1: weight transpose + bf16 convert.  w[1024][1024] f32 -> wt[n][k] bf16
// ---------------------------------------------------------------------------
__global__ __launch_bounds__(256) void wtrans_kernel(
    const float* w0, const float* w1, const float* w2, const float* w3,
    unsigned short* t0, unsigned short* t1, unsigned short* t2, unsigned short* t3)
{
    __shared__ unsigned short tile[64][80];  // pad: 160B row, 16B-aligned
    const int z = blockIdx.z;
    const float* w = (z == 0) ? w0 : (z == 1) ? w1 : (z == 2) ? w2 : w3;
    unsigned short* wt = (z == 0) ? t0 : (z == 1) ? t1 : (z == 2) ? t2 : t3;
    const int n0 = blockIdx.x * 64, k0 = blockIdx.y * 64;
    const int t = threadIdx.x;
#pragma unroll
    for (int i = 0; i < 4; i++) {
        int chunk = t + i * 256;             // 1024 float4 chunks
        int row = chunk >> 4, c4 = chunk & 15;
        float4 v = *(const float4*)(w + (size_t)(k0 + row) * 1024 + n0 + c4 * 4);
        tile[c4 * 4 + 0][row] = f2bf(v.x);
        tile[c4 * 4 + 1][row] = f2bf(v.y);
        tile[c4 * 4 + 2][row] = f2bf(v.z);
        tile[c4 * 4 + 3][row] = f2bf(v.w);
    }
    __syncthreads();
#pragma unroll
    for (int i = 0; i < 2; i++) {
        int idx = t + i * 256;               // 512 chunks of 8 bf16
        int row = idx >> 3, ch = idx & 7;
        uint4 vv = *(const uint4*)(&tile[row][ch * 8]);
        *(uint4*)(wt + (size_t)(n0 + row) * 1024 + k0 + ch * 8) = vv;
    }
}

// ---------------------------------------------------------------------------
// Shared GEMM core: C[128x64] tile, K=1024, BK=64, 4 waves (each 32 rows x 64 cols)
// A: [4096][1024] f32 (convert on stage) or bf16.  B: Wt bf16 [n][k].
// ---------------------------------------------------------------------------
template <bool AF32>
DEVI void gemm_core(const char* Ab, const char* Bb, char* As, char* Bs,
                    int m0, int n0, f32x4 (&acc)[2][4])
{
    const int t = threadIdx.x;
    const int w = t >> 6, l = t & 63, l15 = l & 15, l4 = l >> 4;
#pragma unroll
    for (int rc = 0; rc < 2; rc++)
#pragma unroll
        for (int cc = 0; cc < 4; cc++) acc[rc][cc] = f32x4{0.f, 0.f, 0.f, 0.f};

#pragma unroll 1
    for (int k0 = 0; k0 < 1024; k0 += 64) {
        __syncthreads();  // previous iteration's frag reads done
        if (AF32) {
#pragma unroll
            for (int i = 0; i < 4; i++) {
                int idx = t + i * 256, row = idx >> 3, ch = idx & 7;
                const float4* gp =
                    (const float4*)(Ab + ((size_t)(m0 + row) * 1024 + k0 + ch * 8) * 4);
                float4 f0 = gp[0], f1 = gp[1];
                uint4 pk = {pack2(f0.x, f0.y), pack2(f0.z, f0.w),
                            pack2(f1.x, f1.y), pack2(f1.z, f1.w)};
                *(uint4*)(As + row * 128 + SWZ(row, ch * 16)) = pk;
            }
        } else {
#pragma unroll
            for (int i = 0; i < 4; i++) {
                int idx = t + i * 256, row = idx >> 3, ch = idx & 7;
                uint4 v = *(const uint4*)(Ab + ((size_t)(m0 + row) * 1024 + k0 + ch * 8) * 2);
                *(uint4*)(As + row * 128 + SWZ(row, ch * 16)) = v;
            }
        }
#pragma unroll
        for (int i = 0; i < 2; i++) {
            int idx = t + i * 256, row = idx >> 3, ch = idx & 7;
            uint4 v = *(const uint4*)(Bb + ((size_t)(n0 + row) * 1024 + k0 + ch * 8) * 2);
            *(uint4*)(Bs + row * 128 + SWZ(row, ch * 16)) = v;
        }
        __syncthreads();

        bf16x8 af[2][2], bfr[4][2];
#pragma unroll
        for (int rc = 0; rc < 2; rc++)
#pragma unroll
            for (int kf = 0; kf < 2; kf++) {
                int row = w * 32 + rc * 16 + l15;
                af[rc][kf] = ldsRead(As + row * 128 + SWZ(row, kf * 64 + l4 * 16));
            }
#pragma unroll
        for (int cc = 0; cc < 4; cc++)
#pragma unroll
            for (int kf = 0; kf < 2; kf++) {
                int row = cc * 16 + l15;
                bfr[cc][kf] = ldsRead(Bs + row * 128 + SWZ(row, kf * 64 + l4 * 16));
            }
#pragma unroll
        for (int kf = 0; kf < 2; kf++)
#pragma unroll
            for (int rc = 0; rc < 2; rc++)
#pragma unroll
                for (int cc = 0; cc < 4; cc++)
                    acc[rc][cc] = __builtin_amdgcn_mfma_f32_16x16x32_bf16(
                        af[rc][kf], bfr[cc][kf], acc[rc][cc], 0, 0, 0);
    }
}

// ---------------------------------------------------------------------------
// Kernel 2: QKV projections.  z=0: Q (scale 0.125, head-split), z=1: K (head-split),
// z=2: V (head-split transposed -> Vt[B,H,64,S]).
// ---------------------------------------------------------------------------
__global__ __launch_bounds__(256) void gemm_proj_kernel(
    const float* x0, const float* x1, const float* x2,
    const unsigned short* wt0, const unsigned short* wt1, const unsigned short* wt2,
    const float* b0, const float* b1, const float* b2,
    unsigned short* y0, unsigned short* y1, unsigned short* y2)
{
    __shared__ __align__(16) char As[128 * 64 * 2];
    __shared__ __align__(16) char Bs[64 * 64 * 2];
    const int z = blockIdx.z;
    const float* X = (z == 0) ? x0 : (z == 1) ? x1 : x2;
    const unsigned short* Wt = (z == 0) ? wt0 : (z == 1) ? wt1 : wt2;
    const float* bias = (z == 0) ? b0 : (z == 1) ? b1 : b2;
    unsigned short* Y = (z == 0) ? y0 : (z == 1) ? y1 : y2;
    const float scale = (z == 0) ? 0.125f : 1.0f;
    const int n0 = blockIdx.x * 64, m0 = blockIdx.y * 128;

    f32x4 acc[2][4];
    gemm_core<true>((const char*)X, (const char*)Wt, As, Bs, m0, n0, acc);

    const int t = threadIdx.x, w = t >> 6, l = t & 63, l15 = l & 15, l4 = l >> 4;
#pragma unroll
    for (int cc = 0; cc < 4; cc++) {
        int col = n0 + cc * 16 + l15;
        float bv = bias[col];
        int h = col >> 6, dh = col & 63;
#pragma unroll
        for (int rc = 0; rc < 2; rc++) {
#pragma unroll
            for (int r = 0; r < 4; r++) {
                int m = m0 + w * 32 + rc * 16 + l4 * 4 + r;
                int bb = m >> 11, s = m & 2047;
                float v = (acc[rc][cc][r] + bv) * scale;
                if (z < 2)
                    Y[(((size_t)(bb * 16 + h) * 2048 + s) << 6) + dh] = f2bf(v);
                else
                    Y[(((size_t)((bb * 16 + h) * 64 + dh)) << 11) + s] = f2bf(v);
            }
        }
    }
}

// ---------------------------------------------------------------------------
// Kernel 3: flash attention.  Block: 4 waves, 64 q-rows, iterate 32 K/V tiles of 64.
// Qh/Kh: [B,H,S,64] bf16 (Q pre-scaled).  Vt: [B,H,64,S] bf16.  ctx: [B,S,1024] bf16.
// ---------------------------------------------------------------------------
__global__ __launch_bounds__(256) void attn_kernel(
    const unsigned short* Qh, const unsigned short* Kh, const unsigned short* Vt,
    unsigned short* ctx)
{
    __shared__ __align__(16) char sm[32768];  // Q 8K | K 8K | V 8K | P 4x2K
    char* Qs = sm;
    char* Ks = sm + 8192;
    char* Vs = sm + 16384;
    const int t = threadIdx.x, w = t >> 6, l = t & 63, l15 = l & 15, l4 = l >> 4;
    char* Ps = sm + 24576 + w * 2048;
    const int q0 = blockIdx.x * 64;
    const int bh = blockIdx.y;  // b*16 + h
    const char* Qb = (const char*)(Qh + ((size_t)bh * 2048 + q0) * 64);
    const char* Kb = (const char*)(Kh + (size_t)bh * 2048 * 64);
    const char* Vb = (const char*)(Vt + (size_t)bh * 64 * 2048);

    // stage Q tile [64 rows][64 dk] swizzled
#pragma unroll
    for (int i = 0; i < 2; i++) {
        int idx = t + i * 256, row = idx >> 3, ch = idx & 7;
        uint4 vv = *(const uint4*)(Qb + (size_t)row * 128 + ch * 16);
        *(uint4*)(Qs + row * 128 + SWZ(row, ch * 16)) = vv;
    }
    __syncthreads();
    bf16x8 qf[2];
    {
        int row = w * 16 + l15;
#pragma unroll
        for (int kf = 0; kf < 2; kf++)
            qf[kf] = ldsRead(Qs + row * 128 + SWZ(row, kf * 64 + l4 * 16));
    }

    f32x4 o[4];
#pragma unroll
    for (int c = 0; c < 4; c++) o[c] = f32x4{0.f, 0.f, 0.f, 0.f};
    float mrow[4] = {-1e30f, -1e30f, -1e30f, -1e30f};
    float lrow[4] = {0.f, 0.f, 0.f, 0.f};

#pragma unroll 1
    for (int kt = 0; kt < 32; kt++) {
        const int k0 = kt * 64;
        __syncthreads();  // prior tile's LDS reads complete
#pragma unroll
        for (int i = 0; i < 2; i++) {
            int idx = t + i * 256, row = idx >> 3, ch = idx & 7;
            uint4 kv = *(const uint4*)(Kb + (size_t)(k0 + row) * 128 + ch * 16);
            *(uint4*)(Ks + row * 128 + SWZ(row, ch * 16)) = kv;
            uint4 vv = *(const uint4*)(Vb + (size_t)row * 4096 + (size_t)k0 * 2 + ch * 16);
            *(uint4*)(Vs + row * 128 + SWZ(row, ch * 16)) = vv;
        }
        __syncthreads();

        // S = Q K^T  (per wave: 16 q-rows x 64 keys)
        f32x4 sacc[4];
#pragma unroll
        for (int c = 0; c < 4; c++) sacc[c] = f32x4{0.f, 0.f, 0.f, 0.f};
#pragma unroll
        for (int cc = 0; cc < 4; cc++) {
#pragma unroll
            for (int kf = 0; kf < 2; kf++) {
                int row = cc * 16 + l15;
                bf16x8 kfrag = ldsRead(Ks + row * 128 + SWZ(row, kf * 64 + l4 * 16));
                sacc[cc] = __builtin_amdgcn_mfma_f32_16x16x32_bf16(qf[kf], kfrag, sacc[cc], 0, 0, 0);
            }
        }

        // online softmax (rows = l4*4+r, reduce over 16 lanes of l15)
        float alpha[4];
#pragma unroll
        for (int r = 0; r < 4; r++) {
            float mx = fmaxf(fmaxf(sacc[0][r], sacc[1][r]), fmaxf(sacc[2][r], sacc[3][r]));
            mx = fmaxf(mx, __shfl_xor(mx, 1));
            mx = fmaxf(mx, __shfl_xor(mx, 2));
            mx = fmaxf(mx, __shfl_xor(mx, 4));
            mx = fmaxf(mx, __shfl_xor(mx, 8));
            float mn = fmaxf(mrow[r], mx);
            alpha[r] = __expf(mrow[r] - mn);
            mrow[r] = mn;
        }
#pragma unroll
        for (int r = 0; r < 4; r++) {
            float s = 0.f;
#pragma unroll
            for (int c = 0; c < 4; c++) {
                float p = __expf(sacc[c][r] - mrow[r]);
                sacc[c][r] = p;
                s += p;
            }
            s += __shfl_xor(s, 1);
            s += __shfl_xor(s, 2);
            s += __shfl_xor(s, 4);
            s += __shfl_xor(s, 8);
            lrow[r] = lrow[r] * alpha[r] + s;
        }

        // P -> per-wave LDS (bf16, swizzled)
#pragma unroll
        for (int c = 0; c < 4; c++) {
#pragma unroll
            for (int r = 0; r < 4; r++) {
                int row = l4 * 4 + r;
                int chunk = c * 2 + (l15 >> 3);
                *(unsigned short*)(Ps + row * 128 + ((chunk ^ (row & 7)) << 4) + (l15 & 7) * 2) =
                    f2bf(sacc[c][r]);
            }
        }
#pragma unroll
        for (int c = 0; c < 4; c++)
#pragma unroll
            for (int r = 0; r < 4; r++) o[c][r] *= alpha[r];

        asm volatile("s_waitcnt lgkmcnt(0)" ::: "memory");
        __builtin_amdgcn_sched_barrier(0);

        // O += P V   (A = P[16x64], B = V[64 keys][64 dv] read from Vt rows)
        bf16x8 pf[2];
        {
            int row = l15;
#pragma unroll
            for (int kf = 0; kf < 2; kf++)
                pf[kf] = ldsRead(Ps + row * 128 + SWZ(row, kf * 64 + l4 * 16));
        }
#pragma unroll
        for (int cd = 0; cd < 4; cd++) {
#pragma unroll
            for (int kf = 0; kf < 2; kf++) {
                int row = cd * 16 + l15;
                bf16x8 vfrag = ldsRead(Vs + row * 128 + SWZ(row, kf * 64 + l4 * 16));
                o[cd] = __builtin_amdgcn_mfma_f32_16x16x32_bf16(pf[kf], vfrag, o[cd], 0, 0, 0);
            }
        }
    }

    const int bb = bh >> 4, h = bh & 15;
#pragma unroll
    for (int cd = 0; cd < 4; cd++) {
#pragma unroll
        for (int r = 0; r < 4; r++) {
            int qrow = q0 + w * 16 + l4 * 4 + r;
            float vv = o[cd][r] / lrow[r];
            ctx[((size_t)(bb * 2048 + qrow) << 10) + h * 64 + cd * 16 + l15] = f2bf(vv);
        }
    }
}

// ---------------------------------------------------------------------------
// Kernel 4: output projection.  ctx bf16 @ Wt_o + b_out -> f32 d_out
// ---------------------------------------------------------------------------
__global__ __launch_bounds__(256) void gemm_out_kernel(
    const unsigned short* ctx, const unsigned short* wto, const float* bias, float* out)
{
    __shared__ __align__(16) char As[128 * 64 * 2];
    __shared__ __align__(16) char Bs[64 * 64 * 2];
    const int n0 = blockIdx.x * 64, m0 = blockIdx.y * 128;
    f32x4 acc[2][4];
    gemm_core<false>((const char*)ctx, (const char*)wto, As, Bs, m0, n0, acc);
    const int t = threadIdx.x, w = t >> 6, l = t & 63, l15 = l & 15, l4 = l >> 4;
#pragma unroll
    for (int cc = 0; cc < 4; cc++) {
        int col = n0 + cc * 16 + l15;
        float bv = bias[col];
#pragma unroll
        for (int rc = 0; rc < 2; rc++)
#pragma unroll
            for (int r = 0; r < 4; r++) {
                int m = m0 + w * 32 + rc * 16 + l4 * 4 + r;
                out[(size_t)m * 1024 + col] = acc[rc][cc][r] + bv;
            }
    }
}

// ---------------------------------------------------------------------------
extern "C" void kernel_launch(void* const* d_in, const int* in_sizes, int n_in,
                              void* d_out, int out_size, void* d_ws, size_t ws_size,
                              hipStream_t stream)
{
    (void)in_sizes; (void)n_in; (void)out_size; (void)ws_size;
    const float* q  = (const float*)d_in[0];
    const float* k  = (const float*)d_in[1];
    const float* v  = (const float*)d_in[2];
    const float* wq = (const float*)d_in[3];
    const float* bq = (const float*)d_in[4];
    const float* wk = (const float*)d_in[5];
    const float* bk = (const float*)d_in[6];
    const float* wv = (const float*)d_in[7];
    const float* bv = (const float*)d_in[8];
    const float* wo = (const float*)d_in[9];
    const float* bo = (const float*)d_in[10];

    char* ws = (char*)d_ws;
    const size_t MB = 1u << 20;
    unsigned short* WTq = (unsigned short*)(ws + 0 * MB);
    unsigned short* WTk = (unsigned short*)(ws + 2 * MB);
    unsigned short* WTv = (unsigned short*)(ws + 4 * MB);
    unsigned short* WTo = (unsigned short*)(ws + 6 * MB);
    unsigned short* QH  = (unsigned short*)(ws + 8 * MB);
    unsigned short* KH  = (unsigned short*)(ws + 16 * MB);
    unsigned short* VT  = (unsigned short*)(ws + 24 * MB);
    unsigned short* CTX = (unsigned short*)(ws + 32 * MB);

    wtrans_kernel<<<dim3(16, 16, 4), 256, 0, stream>>>(wq, wk, wv, wo, WTq, WTk, WTv, WTo);
    gemm_proj_kernel<<<dim3(16, 32, 3), 256, 0, stream>>>(q, k, v, WTq, WTk, WTv,
                                                          bq, bk, bv, QH, KH, VT);
    attn_kernel<<<dim3(32, 32), 256, 0, stream>>>(QH, KH, VT, CTX);
    gemm_out_kernel<<<dim3(16, 32), 256, 0, stream>>>(CTX, WTo, bo, (float*)d_out);
}